// Round 4
// baseline (108.047 us; speedup 1.0000x reference)
//
#include <hip/hip_runtime.h>

#define BB 4
#define NN 8192

typedef _Float16 f16;
typedef _Float16 f16x8 __attribute__((ext_vector_type(8)));
typedef float f32x16 __attribute__((ext_vector_type(16)));

// ws layout: 4 packed f16 arrays (1 MB each) then float partials (512 KB)
#define SZ_PACK (BB * NN * 16)          // f16 elements per packed array
#define OFF_PART_BYTES (4 * SZ_PACK * 2)

// ---------------- K1: build packed K-slot records ----------------
// A-role: [-2ah(3), -2ah(3), -2al(3), a2h, a2l, 1, 1, 0,0,0]
// B-role: [ bh(3),   bl(3),   bh(3),  1, 1, b2h, b2l, 0,0,0]
__global__ __launch_bounds__(256) void k_init(
    const float* __restrict__ pr, const float* __restrict__ gt,
    const int* __restrict__ valid,
    f16* __restrict__ APR, f16* __restrict__ BGT,
    f16* __restrict__ AGT, f16* __restrict__ BPR) {
  int i = blockIdx.x * 256 + threadIdx.x;
  if (i >= BB * NN) return;
  float px = pr[3 * i], py = pr[3 * i + 1], pz = pr[3 * i + 2];
  float gx = gt[3 * i], gy = gt[3 * i + 1], gz = gt[3 * i + 2];
  int vld = valid[i] != 0;

  f16 phx = (f16)px, phy = (f16)py, phz = (f16)pz;
  f16 plx = (f16)(px - (float)phx), ply = (f16)(py - (float)phy), plz = (f16)(pz - (float)phz);
  float p2 = px * px + py * py + pz * pz;
  f16 p2h = (f16)p2, p2l = (f16)(p2 - (float)p2h);

  f16 ghx = (f16)gx, ghy = (f16)gy, ghz = (f16)gz;
  f16 glx = (f16)(gx - (float)ghx), gly = (f16)(gy - (float)ghy), glz = (f16)(gz - (float)ghz);
  float g2 = gx * gx + gy * gy + gz * gz;
  f16 g2h = (f16)g2, g2l = (f16)(g2 - (float)g2h);
  f16 g2hm = vld ? g2h : (f16)32768.0f;
  f16 g2lm = vld ? g2l : (f16)0.0f;

  const f16 one = (f16)1.0f, zero = (f16)0.0f;
  union Rec { f16 h[16]; uint4 u[2]; };

  Rec ra;  // APR
  ra.h[0] = (f16)(-2.f * (float)phx); ra.h[1] = (f16)(-2.f * (float)phy); ra.h[2] = (f16)(-2.f * (float)phz);
  ra.h[3] = ra.h[0]; ra.h[4] = ra.h[1]; ra.h[5] = ra.h[2];
  ra.h[6] = (f16)(-2.f * (float)plx); ra.h[7] = (f16)(-2.f * (float)ply); ra.h[8] = (f16)(-2.f * (float)plz);
  ra.h[9] = p2h; ra.h[10] = p2l; ra.h[11] = one; ra.h[12] = one;
  ra.h[13] = zero; ra.h[14] = zero; ra.h[15] = zero;
  ((uint4*)APR)[2 * i] = ra.u[0]; ((uint4*)APR)[2 * i + 1] = ra.u[1];

  Rec rb;  // BPR (pr as columns, unmasked)
  rb.h[0] = phx; rb.h[1] = phy; rb.h[2] = phz;
  rb.h[3] = plx; rb.h[4] = ply; rb.h[5] = plz;
  rb.h[6] = phx; rb.h[7] = phy; rb.h[8] = phz;
  rb.h[9] = one; rb.h[10] = one; rb.h[11] = p2h; rb.h[12] = p2l;
  rb.h[13] = zero; rb.h[14] = zero; rb.h[15] = zero;
  ((uint4*)BPR)[2 * i] = rb.u[0]; ((uint4*)BPR)[2 * i + 1] = rb.u[1];

  Rec rc;  // AGT (gt as rows, unmasked |g|^2)
  rc.h[0] = (f16)(-2.f * (float)ghx); rc.h[1] = (f16)(-2.f * (float)ghy); rc.h[2] = (f16)(-2.f * (float)ghz);
  rc.h[3] = rc.h[0]; rc.h[4] = rc.h[1]; rc.h[5] = rc.h[2];
  rc.h[6] = (f16)(-2.f * (float)glx); rc.h[7] = (f16)(-2.f * (float)gly); rc.h[8] = (f16)(-2.f * (float)glz);
  rc.h[9] = g2h; rc.h[10] = g2l; rc.h[11] = one; rc.h[12] = one;
  rc.h[13] = zero; rc.h[14] = zero; rc.h[15] = zero;
  ((uint4*)AGT)[2 * i] = rc.u[0]; ((uint4*)AGT)[2 * i + 1] = rc.u[1];

  Rec rd;  // BGT (gt as columns, masked: invalid -> +32768 in d^2)
  rd.h[0] = ghx; rd.h[1] = ghy; rd.h[2] = ghz;
  rd.h[3] = glx; rd.h[4] = gly; rd.h[5] = glz;
  rd.h[6] = ghx; rd.h[7] = ghy; rd.h[8] = ghz;
  rd.h[9] = one; rd.h[10] = one; rd.h[11] = g2hm; rd.h[12] = g2lm;
  rd.h[13] = zero; rd.h[14] = zero; rd.h[15] = zero;
  ((uint4*)BGT)[2 * i] = rd.u[0]; ((uint4*)BGT)[2 * i + 1] = rd.u[1];
}

// ---------------- K2: MFMA distance pass, row-min partials ----------------
// grid 1024: p(1) | b(2) | half(1) | wgrow(6). wg = 4 waves x 32 rows = 128 rows,
// cols = half*4096 .. +4096 in 4 chunks of 1024 (LDS 32 KB, 4 wg/CU).
__global__ __launch_bounds__(256, 4) void k_dist(
    const f16* __restrict__ APR, const f16* __restrict__ BGT,
    const f16* __restrict__ AGT, const f16* __restrict__ BPR,
    float* __restrict__ partial) {
  __shared__ f16 lds[2 * 1024 * 8];   // [region q][point j][8 slots] = 32 KB
  int id = blockIdx.x;
  int wgrow = id & 63;
  int half  = (id >> 6) & 1;
  int b     = (id >> 7) & 3;
  int p     = id >> 9;
  const f16* A  = p ? AGT : APR;
  const f16* Bv = p ? BPR : BGT;
  int tid = threadIdx.x;
  int wave = tid >> 6, lane = tid & 63;
  int nn = lane & 31, q = lane >> 5;

  // persistent A fragment: A[m=lane&31][k=(lane>>5)*8 + j]
  const f16* Ab = A + ((size_t)b * NN + wgrow * 128 + wave * 32 + nn) * 16 + q * 8;
  f16x8 af = *(const f16x8*)Ab;

  f32x16 zc = {};        // zero C (hoisted by compiler)
  f32x16 m;
#pragma unroll
  for (int i = 0; i < 16; ++i) m[i] = 1e38f;

  const uint4* gsrc = (const uint4*)(Bv + ((size_t)b * NN + half * 4096) * 16);
  uint4* ldsu = (uint4*)lds;
  const f16x8* lf = (const f16x8*)lds;

  for (int chunk = 0; chunk < 4; ++chunk) {
    const uint4* src = gsrc + (size_t)chunk * 2048;
#pragma unroll
    for (int k = 0; k < 8; ++k) {
      int u = tid + 256 * k;        // u = 2*j + r
      uint4 v = src[u];
      ldsu[(u & 1) * 1024 + (u >> 1)] = v;
    }
    __syncthreads();
#pragma unroll 8
    for (int t = 0; t < 32; ++t) {
      f16x8 bf = lf[q * 1024 + t * 32 + nn];   // B[n][k=q*8+j], native stride-16
      f32x16 d = __builtin_amdgcn_mfma_f32_32x32x16_f16(af, bf, zc, 0, 0, 0);
#pragma unroll
      for (int i = 0; i < 16; ++i) m[i] = fminf(m[i], d[i]);
    }
    __syncthreads();
  }

  // min over the 32 column-lanes (xor masks stay within 32-lane halves)
#pragma unroll
  for (int i = 0; i < 16; ++i) {
    float v = m[i];
    v = fminf(v, __shfl_xor(v, 1, 64));
    v = fminf(v, __shfl_xor(v, 2, 64));
    v = fminf(v, __shfl_xor(v, 4, 64));
    v = fminf(v, __shfl_xor(v, 8, 64));
    v = fminf(v, __shfl_xor(v, 16, 64));
    m[i] = fmaxf(v, 0.0f);          // clamp tiny negative rounding
  }

  // C/D layout: col=lane&31, row=(reg&3)+8*(reg>>2)+4*(lane>>5)
  float* pb = partial + (((size_t)(p * 4 + b) * 2 + half) * NN) + wgrow * 128 + wave * 32;
#pragma unroll
  for (int reg = 0; reg < 16; ++reg) {
    int rit = (reg & 3) + 8 * (reg >> 2) + 4 * q;
    if ((lane & 31) == reg) pb[rit] = m[reg];
  }
}

// ---------------- K3: single-block final reduction ----------------
__global__ __launch_bounds__(1024) void k_red(
    const float* __restrict__ partial, const int* __restrict__ valid,
    float* __restrict__ out) {
  int tid = threadIdx.x;
  float sA[4] = {0, 0, 0, 0}, sC[4] = {0, 0, 0, 0}, sN[4] = {0, 0, 0, 0};
#pragma unroll
  for (int g = 0; g < 8; ++g) {
    int pp = g >> 2, bb = g & 3;
    const float* pb = partial + (size_t)g * 2 * NN;
    for (int r = tid; r < NN; r += 1024) {
      float v = fminf(pb[r], pb[NN + r]);
      if (pp == 0) {
        sA[bb] += v;
      } else {
        int vld = valid[bb * NN + r] != 0;
        sC[bb] += vld ? v : 0.0f;
        sN[bb] += vld ? 1.0f : 0.0f;
      }
    }
  }
  float vals[12] = {sA[0], sA[1], sA[2], sA[3], sC[0], sC[1], sC[2], sC[3],
                    sN[0], sN[1], sN[2], sN[3]};
  __shared__ float red[16][12];
  int wave = tid >> 6, lane = tid & 63;
#pragma unroll
  for (int k = 0; k < 12; ++k) {
    float v = vals[k];
    v += __shfl_xor(v, 1, 64);
    v += __shfl_xor(v, 2, 64);
    v += __shfl_xor(v, 4, 64);
    v += __shfl_xor(v, 8, 64);
    v += __shfl_xor(v, 16, 64);
    v += __shfl_xor(v, 32, 64);
    if (lane == 0) red[wave][k] = v;
  }
  __syncthreads();
  if (tid == 0) {
    float a = 0.f, c = 0.f;
    for (int bb = 0; bb < 4; ++bb) {
      float tA = 0.f, tC = 0.f, tN = 0.f;
      for (int w = 0; w < 16; ++w) {
        tA += red[w][bb]; tC += red[w][4 + bb]; tN += red[w][8 + bb];
      }
      a += tA / (float)NN;
      c += tC / fmaxf(tN, 1.0f);
    }
    out[0] = 0.5f * (a + c);   // 2*(a/4 + c/4)
  }
}

extern "C" void kernel_launch(void* const* d_in, const int* in_sizes, int n_in,
                              void* d_out, int out_size, void* d_ws, size_t ws_size,
                              hipStream_t stream) {
  const float* pr    = (const float*)d_in[0];
  const float* gt    = (const float*)d_in[1];
  const int*   valid = (const int*)d_in[2];

  f16* base = (f16*)d_ws;
  f16* APR = base;
  f16* BGT = base + SZ_PACK;
  f16* AGT = base + 2 * SZ_PACK;
  f16* BPR = base + 3 * SZ_PACK;
  float* partial = (float*)((char*)d_ws + OFF_PART_BYTES);

  k_init<<<(BB * NN) / 256, 256, 0, stream>>>(pr, gt, valid, APR, BGT, AGT, BPR);
  k_dist<<<1024, 256, 0, stream>>>(APR, BGT, AGT, BPR, partial);
  k_red<<<1, 1024, 0, stream>>>(partial, valid, (float*)d_out);
}

// Round 5
// 89.835 us; speedup vs baseline: 1.2027x; 1.2027x over previous
//
#include <hip/hip_runtime.h>

#define BB 4
#define NN 8192

typedef _Float16 f16;
typedef _Float16 f16x8 __attribute__((ext_vector_type(8)));
typedef float f32x16 __attribute__((ext_vector_type(16)));

// ws layout: 4 packed f16 arrays (1 MB each), float partials (512 KB), res (16 f)
#define SZ_PACK (BB * NN * 16)          // f16 elements per packed array
#define OFF_PART_BYTES (4 * SZ_PACK * 2)
#define OFF_RES_BYTES (OFF_PART_BYTES + 16 * NN * 4)

// ---------------- K1: build packed K-slot records ----------------
// A-role: [-2ah(3), -2ah(3), -2al(3), a2h, a2l, 1, 1, 0,0,0]
// B-role: [ bh(3),   bl(3),   bh(3),  1, 1, b2h, b2l, 0,0,0]
// d^2 = ah.bh*-2 (exact-split residuals) + |a|^2 + |b|^2; invalid gt -> +32768
__global__ __launch_bounds__(256) void k_init(
    const float* __restrict__ pr, const float* __restrict__ gt,
    const int* __restrict__ valid,
    f16* __restrict__ APR, f16* __restrict__ BGT,
    f16* __restrict__ AGT, f16* __restrict__ BPR,
    float* __restrict__ res) {
  int i = blockIdx.x * 256 + threadIdx.x;
  if (blockIdx.x == 0 && threadIdx.x < 16) res[threadIdx.x] = 0.0f;
  if (i >= BB * NN) return;
  float px = pr[3 * i], py = pr[3 * i + 1], pz = pr[3 * i + 2];
  float gx = gt[3 * i], gy = gt[3 * i + 1], gz = gt[3 * i + 2];
  int vld = valid[i] != 0;

  f16 phx = (f16)px, phy = (f16)py, phz = (f16)pz;
  f16 plx = (f16)(px - (float)phx), ply = (f16)(py - (float)phy), plz = (f16)(pz - (float)phz);
  float p2 = px * px + py * py + pz * pz;
  f16 p2h = (f16)p2, p2l = (f16)(p2 - (float)p2h);

  f16 ghx = (f16)gx, ghy = (f16)gy, ghz = (f16)gz;
  f16 glx = (f16)(gx - (float)ghx), gly = (f16)(gy - (float)ghy), glz = (f16)(gz - (float)ghz);
  float g2 = gx * gx + gy * gy + gz * gz;
  f16 g2h = (f16)g2, g2l = (f16)(g2 - (float)g2h);
  f16 g2hm = vld ? g2h : (f16)32768.0f;
  f16 g2lm = vld ? g2l : (f16)0.0f;

  const f16 one = (f16)1.0f, zero = (f16)0.0f;
  union Rec { f16 h[16]; uint4 u[2]; };

  Rec ra;  // APR
  ra.h[0] = (f16)(-2.f * (float)phx); ra.h[1] = (f16)(-2.f * (float)phy); ra.h[2] = (f16)(-2.f * (float)phz);
  ra.h[3] = ra.h[0]; ra.h[4] = ra.h[1]; ra.h[5] = ra.h[2];
  ra.h[6] = (f16)(-2.f * (float)plx); ra.h[7] = (f16)(-2.f * (float)ply); ra.h[8] = (f16)(-2.f * (float)plz);
  ra.h[9] = p2h; ra.h[10] = p2l; ra.h[11] = one; ra.h[12] = one;
  ra.h[13] = zero; ra.h[14] = zero; ra.h[15] = zero;
  ((uint4*)APR)[2 * i] = ra.u[0]; ((uint4*)APR)[2 * i + 1] = ra.u[1];

  Rec rb;  // BPR
  rb.h[0] = phx; rb.h[1] = phy; rb.h[2] = phz;
  rb.h[3] = plx; rb.h[4] = ply; rb.h[5] = plz;
  rb.h[6] = phx; rb.h[7] = phy; rb.h[8] = phz;
  rb.h[9] = one; rb.h[10] = one; rb.h[11] = p2h; rb.h[12] = p2l;
  rb.h[13] = zero; rb.h[14] = zero; rb.h[15] = zero;
  ((uint4*)BPR)[2 * i] = rb.u[0]; ((uint4*)BPR)[2 * i + 1] = rb.u[1];

  Rec rc;  // AGT
  rc.h[0] = (f16)(-2.f * (float)ghx); rc.h[1] = (f16)(-2.f * (float)ghy); rc.h[2] = (f16)(-2.f * (float)ghz);
  rc.h[3] = rc.h[0]; rc.h[4] = rc.h[1]; rc.h[5] = rc.h[2];
  rc.h[6] = (f16)(-2.f * (float)glx); rc.h[7] = (f16)(-2.f * (float)gly); rc.h[8] = (f16)(-2.f * (float)glz);
  rc.h[9] = g2h; rc.h[10] = g2l; rc.h[11] = one; rc.h[12] = one;
  rc.h[13] = zero; rc.h[14] = zero; rc.h[15] = zero;
  ((uint4*)AGT)[2 * i] = rc.u[0]; ((uint4*)AGT)[2 * i + 1] = rc.u[1];

  Rec rd;  // BGT (masked)
  rd.h[0] = ghx; rd.h[1] = ghy; rd.h[2] = ghz;
  rd.h[3] = glx; rd.h[4] = gly; rd.h[5] = glz;
  rd.h[6] = ghx; rd.h[7] = ghy; rd.h[8] = ghz;
  rd.h[9] = one; rd.h[10] = one; rd.h[11] = g2hm; rd.h[12] = g2lm;
  rd.h[13] = zero; rd.h[14] = zero; rd.h[15] = zero;
  ((uint4*)BGT)[2 * i] = rd.u[0]; ((uint4*)BGT)[2 * i + 1] = rd.u[1];
}

// ---------------- K2: MFMA distance pass, row-min partials ----------------
// grid 1024: p(1) | b(2) | half(1) | wgrow(6). wg = 4 waves x 32 rows = 128 rows,
// cols = half*4096 .. +4096 in 4 chunks of 1024 (LDS 32 KB, 4 wg/CU).
__global__ __launch_bounds__(256, 4) void k_dist(
    const f16* __restrict__ APR, const f16* __restrict__ BGT,
    const f16* __restrict__ AGT, const f16* __restrict__ BPR,
    float* __restrict__ partial) {
  __shared__ f16 lds[2 * 1024 * 8];   // [region q][point j][8 slots] = 32 KB
  int id = blockIdx.x;
  int wgrow = id & 63;
  int half  = (id >> 6) & 1;
  int b     = (id >> 7) & 3;
  int p     = id >> 9;
  const f16* A  = p ? AGT : APR;
  const f16* Bv = p ? BPR : BGT;
  int tid = threadIdx.x;
  int wave = tid >> 6, lane = tid & 63;
  int nn = lane & 31, q = lane >> 5;

  // persistent A fragment: A[m=lane&31][k=(lane>>5)*8 + j]
  const f16* Ab = A + ((size_t)b * NN + wgrow * 128 + wave * 32 + nn) * 16 + q * 8;
  f16x8 af = *(const f16x8*)Ab;

  f32x16 zc = {};
  f32x16 m;
#pragma unroll
  for (int i = 0; i < 16; ++i) m[i] = 1e38f;

  const uint4* gsrc = (const uint4*)(Bv + ((size_t)b * NN + half * 4096) * 16);
  uint4* ldsu = (uint4*)lds;
  const f16x8* lf = (const f16x8*)lds;

  for (int chunk = 0; chunk < 4; ++chunk) {
    const uint4* src = gsrc + (size_t)chunk * 2048;
#pragma unroll
    for (int k = 0; k < 8; ++k) {
      int u = tid + 256 * k;        // u = 2*j + r
      ldsu[(u & 1) * 1024 + (u >> 1)] = src[u];
    }
    __syncthreads();
    // 2 tiles per iteration: registers stay bounded (2x16 d + 16 m + 16 zc + frags)
    for (int t = 0; t < 32; t += 2) {
      f16x8 b0 = lf[q * 1024 + t * 32 + nn];
      f16x8 b1 = lf[q * 1024 + (t + 1) * 32 + nn];
      f32x16 d0 = __builtin_amdgcn_mfma_f32_32x32x16_f16(af, b0, zc, 0, 0, 0);
      f32x16 d1 = __builtin_amdgcn_mfma_f32_32x32x16_f16(af, b1, zc, 0, 0, 0);
#pragma unroll
      for (int i = 0; i < 16; ++i)
        m[i] = fminf(fminf(d0[i], d1[i]), m[i]);   // v_min3_f32
    }
    __syncthreads();
  }

  // col-lane min (xor within 32-lane halves)
#pragma unroll
  for (int i = 0; i < 16; ++i) {
    float v = m[i];
    v = fminf(v, __shfl_xor(v, 1, 64));
    v = fminf(v, __shfl_xor(v, 2, 64));
    v = fminf(v, __shfl_xor(v, 4, 64));
    v = fminf(v, __shfl_xor(v, 8, 64));
    v = fminf(v, __shfl_xor(v, 16, 64));
    m[i] = fmaxf(v, 0.0f);
  }

  // C/D layout: col=lane&31, row=(reg&3)+8*(reg>>2)+4*(lane>>5)
  float* pb = partial + (((size_t)(p * 4 + b) * 2 + half) * NN) + wgrow * 128 + wave * 32;
#pragma unroll
  for (int reg = 0; reg < 16; ++reg) {
    int rit = (reg & 3) + 8 * (reg >> 2) + 4 * q;
    if ((lane & 31) == reg) pb[rit] = m[reg];
  }
}

// ---------------- K3: parallel reduction into res[12] ----------------
// grid 64: g = bid>>3 (0..7 = {p,b}), seg = bid&7 (1024 rows each)
__global__ __launch_bounds__(256) void k_red(
    const float* __restrict__ partial, const int* __restrict__ valid,
    float* __restrict__ res) {
  int g = blockIdx.x >> 3, seg = blockIdx.x & 7;
  int pp = g >> 2, bb = g & 3;
  int tid = threadIdx.x;
  const float* pb = partial + (size_t)g * 2 * NN;

  float sum = 0.0f, cnt = 0.0f;
#pragma unroll
  for (int k = 0; k < 4; ++k) {
    int r = seg * 1024 + tid + 256 * k;
    float v = fminf(pb[r], pb[NN + r]);
    if (pp == 0) {
      sum += v;
    } else {
      int vld = valid[bb * NN + r] != 0;
      sum += vld ? v : 0.0f;
      cnt += vld ? 1.0f : 0.0f;
    }
  }
  __shared__ float r1[256], r2[256];
  r1[tid] = sum; r2[tid] = cnt;
  __syncthreads();
  for (int off = 128; off > 0; off >>= 1) {
    if (tid < off) { r1[tid] += r1[tid + off]; r2[tid] += r2[tid + off]; }
    __syncthreads();
  }
  if (tid == 0) {
    if (pp == 0) {
      atomicAdd(&res[bb], r1[0]);
    } else {
      atomicAdd(&res[4 + bb], r1[0]);
      atomicAdd(&res[8 + bb], r2[0]);
    }
  }
}

// ---------------- K4: final scalar ----------------
__global__ void k_final(const float* __restrict__ res, float* __restrict__ out) {
  if (threadIdx.x == 0 && blockIdx.x == 0) {
    float a = 0.f, c = 0.f;
    for (int bb = 0; bb < 4; ++bb) {
      a += res[bb] / (float)NN;
      c += res[4 + bb] / fmaxf(res[8 + bb], 1.0f);
    }
    out[0] = 0.5f * (a + c);   // 2*(a/4 + c/4)
  }
}

extern "C" void kernel_launch(void* const* d_in, const int* in_sizes, int n_in,
                              void* d_out, int out_size, void* d_ws, size_t ws_size,
                              hipStream_t stream) {
  const float* pr    = (const float*)d_in[0];
  const float* gt    = (const float*)d_in[1];
  const int*   valid = (const int*)d_in[2];

  f16* base = (f16*)d_ws;
  f16* APR = base;
  f16* BGT = base + SZ_PACK;
  f16* AGT = base + 2 * SZ_PACK;
  f16* BPR = base + 3 * SZ_PACK;
  float* partial = (float*)((char*)d_ws + OFF_PART_BYTES);
  float* res     = (float*)((char*)d_ws + OFF_RES_BYTES);

  k_init<<<(BB * NN) / 256, 256, 0, stream>>>(pr, gt, valid, APR, BGT, AGT, BPR, res);
  k_dist<<<1024, 256, 0, stream>>>(APR, BGT, AGT, BPR, partial);
  k_red<<<64, 256, 0, stream>>>(partial, valid, res);
  k_final<<<1, 64, 0, stream>>>(res, (float*)d_out);
}